// Round 4
// baseline (514.448 us; speedup 1.0000x reference)
//
#include <hip/hip_runtime.h>
#include <stdint.h>
#include <stddef.h>

#define IN_F 4096
#define OUT_F 4096

typedef int i32x4 __attribute__((ext_vector_type(4)));
typedef float f32x4 __attribute__((ext_vector_type(4)));

// ---------- helpers ----------

__device__ static inline void async16(const void* g, void* l) {
    __builtin_amdgcn_global_load_lds(
        (const __attribute__((address_space(1))) unsigned int*)g,
        (__attribute__((address_space(3))) unsigned int*)l,
        16, 0, 0);
}

__device__ static inline double wred_d(double v) {
#pragma unroll
    for (int o = 32; o > 0; o >>= 1) v += __shfl_down(v, o, 64);
    return v;
}

__device__ static inline int wred_i(int v) {
#pragma unroll
    for (int o = 32; o > 0; o >>= 1) v += __shfl_down(v, o, 64);
    return v;
}

__device__ static inline float wred_max(float v) {
#pragma unroll
    for (int o = 32; o > 0; o >>= 1) v = fmaxf(v, __shfl_down(v, o, 64));
    return v;
}

// ---------- K1: fused per-row stats + ternarize -> T i8 {-1,0,1} ----------
// one block (256 thr) per input row; row cached in LDS (single HBM read of w)

__global__ __launch_bounds__(256) void rowstats_tern_kernel(
    const float* __restrict__ w,
    float* __restrict__ alpha_o,
    int8_t* __restrict__ T) {
    __shared__ float rowbuf[OUT_F];          // 16 KB
    __shared__ double sh_s[4], sh_m[4];
    __shared__ int sh_c[4];
    const int row = blockIdx.x;
    const int t = threadIdx.x;
    const int lane = t & 63, wv = t >> 6;
    const float4* wr = (const float4*)(w + (size_t)row * OUT_F);

    // pass 1: load row -> LDS, accumulate sum|w| in double
    double s = 0.0;
#pragma unroll
    for (int it = 0; it < 4; ++it) {
        float4 v = wr[t + it * 256];
        ((float4*)rowbuf)[t + it * 256] = v;
        s += (double)fabsf(v.x) + (double)fabsf(v.y) +
             (double)fabsf(v.z) + (double)fabsf(v.w);
    }
    double sw = wred_d(s);
    if (lane == 0) sh_s[wv] = sw;
    __syncthreads();
    const double delta = (sh_s[0] + sh_s[1] + sh_s[2] + sh_s[3]) *
                         (0.7 / (double)OUT_F);

    // pass 2 from LDS: masked sum/count + ternarize + coalesced i8 stores
    int8_t* trow = T + (size_t)row * OUT_F;
    double ms = 0.0;
    int cnt = 0;
#pragma unroll
    for (int k = 0; k < 16; ++k) {
        float v = rowbuf[k * 256 + t];
        double a = (double)fabsf(v);
        if (a > delta) { ms += a; ++cnt; }
        int8_t q = 0;
        if ((double)v > delta)       q = 1;
        else if ((double)v < -delta) q = -1;
        trow[k * 256 + t] = q;
    }
    double msw = wred_d(ms);
    int cw = wred_i(cnt);
    if (lane == 0) { sh_m[wv] = msw; sh_c[wv] = cw; }
    __syncthreads();
    if (t == 0) {
        double mtot = sh_m[0] + sh_m[1] + sh_m[2] + sh_m[3];
        int ctot = sh_c[0] + sh_c[1] + sh_c[2] + sh_c[3];
        alpha_o[row] = (float)(mtot / (double)ctot);
    }
}

// ---------- K2: i8 transpose T[IN][OUT] -> Tt[OUT][IN] ----------
// 64x64 byte tile via LDS; 4B reads, 8B writes, both coalesced

__global__ __launch_bounds__(256) void transpose_i8_kernel(
    const int8_t* __restrict__ T,
    int8_t* __restrict__ Tt) {
    __shared__ int8_t lds[64][72];  // 72: 8B-aligned rows, spreads banks
    const int t = threadIdx.x;
    const int i0 = blockIdx.y * 64;  // IN
    const int j0 = blockIdx.x * 64;  // OUT

#pragma unroll
    for (int it = 0; it < 4; ++it) {
        int idx = it * 256 + t;
        int r = idx >> 4;          // row (IN dim)
        int c4 = idx & 15;         // 4-byte chunk (OUT dim)
        uchar4 v = *(const uchar4*)(T + (size_t)(i0 + r) * OUT_F + j0 + c4 * 4);
        lds[c4 * 4 + 0][r] = (int8_t)v.x;
        lds[c4 * 4 + 1][r] = (int8_t)v.y;
        lds[c4 * 4 + 2][r] = (int8_t)v.z;
        lds[c4 * 4 + 3][r] = (int8_t)v.w;
    }
    __syncthreads();
#pragma unroll
    for (int it = 0; it < 2; ++it) {
        int idx = it * 256 + t;
        int rr = idx >> 3;         // row (OUT dim)
        int cc = idx & 7;          // 8-byte chunk (IN dim)
        unsigned long long v = *(const unsigned long long*)&lds[rr][cc * 8];
        *(unsigned long long*)(Tt + (size_t)(j0 + rr) * IN_F + i0 + cc * 8) = v;
    }
}

// ---------- K3: per-batch-row quantize Xq = rint(x*alpha * 127/rowmax) ----------

__global__ __launch_bounds__(256) void xquant_kernel(
    const float* __restrict__ x,
    const float* __restrict__ alpha,
    int8_t* __restrict__ xq,
    float* __restrict__ scale_o) {
    __shared__ float rowbuf[IN_F];   // xs values, 16 KB
    __shared__ float sh_mx[4];
    const int row = blockIdx.x;
    const int t = threadIdx.x;
    const int lane = t & 63, wv = t >> 6;
    const float4* xr = (const float4*)(x + (size_t)row * IN_F);
    const float4* ar = (const float4*)alpha;

    float mx = 0.0f;
#pragma unroll
    for (int it = 0; it < 4; ++it) {
        float4 v = xr[t + it * 256];
        float4 a = ar[t + it * 256];
        v.x *= a.x; v.y *= a.y; v.z *= a.z; v.w *= a.w;
        ((float4*)rowbuf)[t + it * 256] = v;
        mx = fmaxf(mx, fmaxf(fmaxf(fabsf(v.x), fabsf(v.y)),
                             fmaxf(fabsf(v.z), fabsf(v.w))));
    }
    float mw = wred_max(mx);
    if (lane == 0) sh_mx[wv] = mw;
    __syncthreads();
    const float rmax = fmaxf(fmaxf(sh_mx[0], sh_mx[1]), fmaxf(sh_mx[2], sh_mx[3]));
    const float inv = (rmax > 0.0f) ? (127.0f / rmax) : 0.0f;

    int8_t* qrow = xq + (size_t)row * IN_F;
#pragma unroll
    for (int k = 0; k < 16; ++k) {
        float v = rowbuf[k * 256 + t];
        qrow[k * 256 + t] = (int8_t)__float2int_rn(v * inv);
    }
    if (t == 0) scale_o[row] = (rmax > 0.0f) ? (rmax / 127.0f) : 1.0f;
}

// ---------- K4: i8 MFMA GEMM, BK=64, chunk-major LDS (conflict-free) ----------
// acc[M,N] = Xq[M,K] * Tq[N,K]^T (exact i32); out = scale[m]*acc + bias[n]
//
// LDS layout: addr of (row r, k-chunk c [16B]) = (r>>4)*1024 + c*256 + (r&15)*16
// -> each fragment read af[i] is the wave reading one CONTIGUOUS 1 KB:
//    uniform 8 accesses/bank, zero conflicts (was 4-way: all lanes on 8 banks).

__global__ __launch_bounds__(256) void gemm_i8_kernel(
    const int8_t* __restrict__ Xq,   // [M,K]
    const int8_t* __restrict__ Tq,   // [N,K]
    const float* __restrict__ scale, // [M]
    const float* __restrict__ bias,  // [N]
    float* __restrict__ out) {
    __shared__ __align__(16) int8_t lds_a[128 * 64];  // 8 KB
    __shared__ __align__(16) int8_t lds_b[128 * 64];  // 8 KB
    const int K = IN_F;
    const int t = threadIdx.x;
    const int lane = t & 63;
    const int wave = t >> 6;
    const int m0 = blockIdx.y * 128;
    const int n0 = blockIdx.x * 128;

    // chunk-major staging: thread t = w*64 + c*16 + m  ->  row w*16+m, chunk c
    const int srow = (t >> 6) * 16 + (t & 15);   // 0..63
    const int scol = ((t >> 4) & 3) * 16;        // k-byte offset 0/16/32/48
    const int8_t* gA0 = Xq + (size_t)(m0 + srow) * K + scol;
    const int8_t* gA1 = Xq + (size_t)(m0 + srow + 64) * K + scol;
    const int8_t* gB0 = Tq + (size_t)(n0 + srow) * K + scol;
    const int8_t* gB1 = Tq + (size_t)(n0 + srow + 64) * K + scol;
    char* lA0 = (char*)lds_a + t * 16;
    char* lA1 = (char*)lds_a + t * 16 + 4096;
    char* lB0 = (char*)lds_b + t * 16;
    char* lB1 = (char*)lds_b + t * 16 + 4096;

    i32x4 acc[4][4];
#pragma unroll
    for (int i = 0; i < 4; ++i)
#pragma unroll
        for (int j = 0; j < 4; ++j)
#pragma unroll
            for (int r = 0; r < 4; ++r) acc[i][j][r] = 0;

    // fragments: lane (lm = lane&15, q = lane>>4) needs row tile*16+lm,
    // k = q*16..q*16+15  ->  addr = tile*1024 + q*256 + lm*16
    const int q = lane >> 4;
    const int lm = lane & 15;
    const int wm = (wave >> 1) << 6;
    const int wn = (wave & 1) << 6;
    const int8_t* pa = lds_a + (wm >> 4) * 1024 + q * 256 + lm * 16;
    const int8_t* pb = lds_b + (wn >> 4) * 1024 + q * 256 + lm * 16;

    for (int k0 = 0; k0 < K; k0 += 64) {
        async16(gA0 + k0, lA0);
        async16(gA1 + k0, lA1);
        async16(gB0 + k0, lB0);
        async16(gB1 + k0, lB1);
        __syncthreads();  // drains vmcnt(0): staging visible in LDS
        i32x4 af[4], bf[4];
#pragma unroll
        for (int i = 0; i < 4; ++i) {
            af[i] = *(const i32x4*)(pa + i * 1024);
            bf[i] = *(const i32x4*)(pb + i * 1024);
        }
#pragma unroll
        for (int i = 0; i < 4; ++i)
#pragma unroll
            for (int j = 0; j < 4; ++j)
                acc[i][j] = __builtin_amdgcn_mfma_i32_16x16x64_i8(
                    af[i], bf[j], acc[i][j], 0, 0, 0);
        __syncthreads();  // protect LDS before next staging
    }

    // epilogue: C/D layout col=lane&15, row=(lane>>4)*4+reg (dtype-independent)
    const int q4 = (lane >> 4) << 2;
#pragma unroll
    for (int i = 0; i < 4; ++i) {
        float sc[4];
#pragma unroll
        for (int r = 0; r < 4; ++r) sc[r] = scale[m0 + wm + i * 16 + q4 + r];
#pragma unroll
        for (int j = 0; j < 4; ++j) {
            int col = n0 + wn + j * 16 + lm;
            float b = bias[col];
#pragma unroll
            for (int r = 0; r < 4; ++r) {
                int row = m0 + wm + i * 16 + q4 + r;
                out[(size_t)row * OUT_F + col] =
                    (float)acc[i][j][r] * sc[r] + b;
            }
        }
    }
}

// ---------- launch ----------

extern "C" void kernel_launch(void* const* d_in, const int* in_sizes, int n_in,
                              void* d_out, int out_size, void* d_ws, size_t ws_size,
                              hipStream_t stream) {
    const float* x = (const float*)d_in[0];
    const float* w = (const float*)d_in[1];
    const float* bias = (const float*)d_in[2];
    float* out = (float*)d_out;
    const int B = in_sizes[0] / IN_F;  // 8192

    // ws layout (48 MB + 48 KB):
    //   [0, 16M)    Tt [OUT][IN] i8 (transposed ternary)
    //   [16M, 32M)  T  [IN][OUT] i8 (temp; dead after K2)
    //   [16M, 48M)  Xq [B][IN] i8 (K3 overwrites T — stream-serial safe)
    //   [48M, ..)   alpha fp32[IN], scale fp32[B]
    char* ws = (char*)d_ws;
    int8_t* Tt = (int8_t*)ws;
    int8_t* T = (int8_t*)(ws + (size_t)16777216);
    int8_t* Xq = (int8_t*)(ws + (size_t)16777216);
    float* alpha = (float*)(ws + (size_t)50331648);
    float* scale = (float*)(ws + (size_t)50331648 + 16384);

    rowstats_tern_kernel<<<IN_F, 256, 0, stream>>>(w, alpha, T);
    transpose_i8_kernel<<<dim3(OUT_F / 64, IN_F / 64), 256, 0, stream>>>(T, Tt);
    xquant_kernel<<<B, 256, 0, stream>>>(x, alpha, Xq, scale);
    gemm_i8_kernel<<<dim3(OUT_F / 128, B / 128), 256, 0, stream>>>(Xq, Tt, scale, bias, out);
}